// Round 17
// baseline (473.306 us; speedup 1.0000x reference)
//
#include <hip/hip_runtime.h>
#include <math.h>

#define BSZ 4
#define Lseq 2048
#define DM 64
#define ED 128
#define NST 32
#define DCONVK 16
#define NLAYERS 4
#define DTRANK 4
#define EPSV 1e-5f
#define NC 256                // chunks along L (chunk == conv tile == gemm tile)
#define TT 8                  // tokens per block (R17: halved for 4 blocks/CU occupancy)

__device__ __forceinline__ float sigf(float x) { return 1.0f / (1.0f + __expf(-x)); }
__device__ __forceinline__ float hsum4(float4 a) { return (a.x + a.y) + (a.z + a.w); }

// inproj: 64 -> 256 for TT tokens; hn in LDS; writes xin (tid<128) / zbuf.
__device__ __forceinline__ void inprojT(
    const float* in_w_l, const float* in_b_l, const float (*hn)[DM],
    float* xin, float* zbuf, size_t t0, int tid)
{
    float4 w4[16];
    const float4* wr = (const float4*)(in_w_l + tid * DM);
    #pragma unroll
    for (int i = 0; i < 16; ++i) w4[i] = wr[i];
    const float bias = in_b_l[tid];
    #pragma unroll 2
    for (int tok = 0; tok < TT; ++tok) {
        const float4* hv4 = (const float4*)&hn[tok][0];
        float4 a4 = make_float4(0.f, 0.f, 0.f, 0.f);
        #pragma unroll
        for (int i = 0; i < 16; ++i) {
            float4 hv = hv4[i];
            a4.x = fmaf(hv.x, w4[i].x, a4.x);
            a4.y = fmaf(hv.y, w4[i].y, a4.y);
            a4.z = fmaf(hv.z, w4[i].z, a4.z);
            a4.w = fmaf(hv.w, w4[i].w, a4.w);
        }
        const float r = bias + hsum4(a4);
        if (tid < ED) xin[(t0 + tok) * ED + tid] = r;
        else          zbuf[(t0 + tok) * ED + (tid - ED)] = r;
    }
}

// ---------------- K_A (layer 0 only): rmsnorm + inproj, TT tokens/block
__global__ __launch_bounds__(256) void k_layer_gemm(
    const float* __restrict__ hin, const float* __restrict__ norm_w,
    const float* __restrict__ in_w, const float* __restrict__ in_b,
    float* __restrict__ xin, float* __restrict__ zb)
{
    const int t0 = blockIdx.x * TT;
    const int tid = threadIdx.x;
    const int lane = tid & 63;
    const int wv = tid >> 6;              // wave -> tokens [wv*2, wv*2+2)
    __shared__ __align__(16) float hn[TT][DM];

    const float nw = norm_w[lane];
    float hval[2];
    #pragma unroll
    for (int j = 0; j < 2; ++j)
        hval[j] = hin[(size_t)(t0 + wv * 2 + j) * DM + lane];

    #pragma unroll
    for (int j = 0; j < 2; ++j) {
        float ss = hval[j] * hval[j];
        #pragma unroll
        for (int off = 32; off; off >>= 1) ss += __shfl_xor(ss, off, 64);
        const float sc = rsqrtf(ss * (1.0f / DM) + EPSV);
        hn[wv * 2 + j][lane] = hval[j] * sc * nw;
    }
    __syncthreads();
    inprojT(in_w, in_b, (const float (*)[DM])hn, xin, zb, (size_t)t0, tid);
}

// ---------------- K_B: conv + silu + xproj + dtproj + local scan — 1 chunk (8 tok)/block
__global__ __launch_bounds__(256) void k_conv_scan(
    const float* __restrict__ xin, const float* __restrict__ conv_w,
    const float* __restrict__ conv_b, const float* __restrict__ xproj_w,
    const float* __restrict__ dtproj_w, const float* __restrict__ dtproj_b,
    const float* __restrict__ A_log,
    float* __restrict__ xc_out, float* __restrict__ delta_out,
    float* __restrict__ Bout, float* __restrict__ Cout,
    float* __restrict__ aprod, float* __restrict__ hloc)
{
    const int blk = blockIdx.x;             // BSZ * NC = 1024 blocks
    const int b   = blk >> 8;               // NC = 256
    const int c   = blk & 255;
    const int l0  = c * TT;
    const size_t t0 = (size_t)b * Lseq + l0;
    const int tid = threadIdx.x;
    const int e = tid & 127, half = tid >> 7;
    __shared__ __align__(16) float xs[(TT + DCONVK - 1) * ED];   // 23 rows, 11.5 KB
    __shared__ __align__(16) float xcs[TT][ED];                   // 4 KB
    __shared__ __align__(16) float Bs[TT][NST];                   // 1 KB
    __shared__ float dts[TT][DTRANK];
    float (*dl)[ED] = (float (*)[ED])xs;    // alias: xs dead after conv phase

    // hoisted global loads (overlap with staging)
    float Aen16[16];
    {
        const float4* a4 = (const float4*)(A_log + e * NST + half * 16);
        #pragma unroll
        for (int i = 0; i < 4; ++i) {
            float4 v = a4[i];
            Aen16[i*4+0] = -__expf(v.x); Aen16[i*4+1] = -__expf(v.y);
            Aen16[i*4+2] = -__expf(v.z); Aen16[i*4+3] = -__expf(v.w);
        }
    }
    float w[DCONVK];
    {
        const float4* cw = (const float4*)(conv_w + e * DCONVK);
        #pragma unroll
        for (int i = 0; i < 4; ++i) {
            float4 cc = cw[i];
            w[i*4+0] = cc.x; w[i*4+1] = cc.y; w[i*4+2] = cc.z; w[i*4+3] = cc.w;
        }
    }
    const float cb = conv_b[e];

    {
        const int NV = (TT + DCONVK - 1) * ED / 4;   // 736
        for (int idx4 = tid; idx4 < NV; idx4 += 256) {
            const int row = idx4 >> 5;
            const int lrow = l0 - (DCONVK - 1) + row;
            float4 v = make_float4(0.f, 0.f, 0.f, 0.f);
            if (lrow >= 0)
                v = ((const float4*)(xin + ((size_t)b * Lseq + lrow) * ED))[idx4 & 31];
            ((float4*)xs)[idx4] = v;
        }
    }
    __syncthreads();

    {   // conv + silu: 4 tokens per (e,half)
        #pragma unroll 2
        for (int j = 0; j < 4; ++j) {
            const int tok = half * 4 + j;
            float acc = cb;
            #pragma unroll
            for (int k = 0; k < DCONVK; ++k)
                acc = fmaf(xs[(tok + k) * ED + e], w[k], acc);
            const float xcv = acc * sigf(acc);
            xcs[tok][e] = xcv;
            xc_out[(t0 + tok) * ED + e] = xcv;
        }
    }
    __syncthreads();   // xs dead from here on

    {   // xproj: wave wv -> tokens [wv*2, wv*2+2); lane = dbc row 0..63
        const int wv = tid >> 6, lane = tid & 63;
        float4 acc[2];
        #pragma unroll
        for (int j = 0; j < 2; ++j) acc[j] = make_float4(0.f, 0.f, 0.f, 0.f);
        #pragma unroll 1
        for (int p = 0; p < 4; ++p) {
            float4 w4[8];
            const float4* wr = (const float4*)(xproj_w + lane * ED + p * 32);
            #pragma unroll
            for (int i = 0; i < 8; ++i) w4[i] = wr[i];
            #pragma unroll
            for (int j = 0; j < 2; ++j) {
                const float4* yv = (const float4*)&xcs[wv * 2 + j][p * 32];
                #pragma unroll
                for (int i = 0; i < 8; ++i) {
                    float4 hv = yv[i];
                    acc[j].x = fmaf(hv.x, w4[i].x, acc[j].x);
                    acc[j].y = fmaf(hv.y, w4[i].y, acc[j].y);
                    acc[j].z = fmaf(hv.z, w4[i].z, acc[j].z);
                    acc[j].w = fmaf(hv.w, w4[i].w, acc[j].w);
                }
            }
        }
        #pragma unroll
        for (int j = 0; j < 2; ++j) {
            const int tok = wv * 2 + j;
            const float v = hsum4(acc[j]);
            if (lane < DTRANK) {
                dts[tok][lane] = v;
            } else if (lane < DTRANK + NST) {
                Bs[tok][lane - DTRANK] = v;
                Bout[(t0 + tok) * NST + (lane - DTRANK)] = v;
            } else {
                Cout[(t0 + tok) * NST + (lane - DTRANK - NST)] = v;
            }
        }
        {   // leftover rows 64..67 (C idx 28..31): lane = 32*tsub + 4*ks + ridx
            const int ridx = lane & 3;             // row
            const int ks   = (lane >> 2) & 7;      // k-slice of 16 floats
            const int tsub = lane >> 5;            // token sub (0/1)
            const int r4   = 64 + ridx;
            const int tok  = wv * 2 + tsub;
            const float4* wr = (const float4*)(xproj_w + r4 * ED + ks * 16);
            const float4* yv = (const float4*)&xcs[tok][ks * 16];
            float4 a4 = make_float4(0.f, 0.f, 0.f, 0.f);
            #pragma unroll
            for (int i = 0; i < 4; ++i) {
                float4 hv = yv[i]; float4 wv4 = wr[i];
                a4.x = fmaf(hv.x, wv4.x, a4.x);
                a4.y = fmaf(hv.y, wv4.y, a4.y);
                a4.z = fmaf(hv.z, wv4.z, a4.z);
                a4.w = fmaf(hv.w, wv4.w, a4.w);
            }
            float v = hsum4(a4);
            v += __shfl_xor(v, 4, 64);
            v += __shfl_xor(v, 8, 64);
            v += __shfl_xor(v, 16, 64);
            if (ks == 0) Cout[(t0 + tok) * NST + (r4 - DTRANK - NST)] = v;
        }
    }
    __syncthreads();

    {   // dtproj + softplus -> dl (aliased LDS) + delta_out
        const float4 dwv = *(const float4*)(dtproj_w + e * DTRANK);
        const float bias = dtproj_b[e];
        #pragma unroll 2
        for (int j = 0; j < 4; ++j) {
            const int tok = half * 4 + j;
            float a = bias;
            a = fmaf(dts[tok][0], dwv.x, a);
            a = fmaf(dts[tok][1], dwv.y, a);
            a = fmaf(dts[tok][2], dwv.z, a);
            a = fmaf(dts[tok][3], dwv.w, a);
            const float sp = fmaxf(a, 0.f) + log1pf(__expf(-fabsf(a)));
            dl[tok][e] = sp;
            delta_out[(t0 + tok) * ED + e] = sp;
        }
    }
    __syncthreads();

    {   // local scan: two 8-state passes (unroll 2)
        float dsum = 0.f;
        #pragma unroll 4
        for (int l = 0; l < TT; ++l) dsum += dl[l][e];

        #pragma unroll 1
        for (int g = 0; g < 2; ++g) {
            const int n0 = half * 16 + g * 8;
            float Aen[8];
            #pragma unroll
            for (int k = 0; k < 8; ++k) Aen[k] = Aen16[g * 8 + k];
            float hs[8];
            #pragma unroll
            for (int k = 0; k < 8; ++k) hs[k] = 0.f;
            #pragma unroll 2
            for (int l = 0; l < TT; ++l) {
                const float de   = dl[l][e];
                const float dexc = de * xcs[l][e];
                const float4 B0 = *(const float4*)&Bs[l][n0];
                const float4 B1 = *(const float4*)&Bs[l][n0 + 4];
                float a;
                a = __expf(de * Aen[0]); hs[0] = fmaf(a, hs[0], B0.x * dexc);
                a = __expf(de * Aen[1]); hs[1] = fmaf(a, hs[1], B0.y * dexc);
                a = __expf(de * Aen[2]); hs[2] = fmaf(a, hs[2], B0.z * dexc);
                a = __expf(de * Aen[3]); hs[3] = fmaf(a, hs[3], B0.w * dexc);
                a = __expf(de * Aen[4]); hs[4] = fmaf(a, hs[4], B1.x * dexc);
                a = __expf(de * Aen[5]); hs[5] = fmaf(a, hs[5], B1.y * dexc);
                a = __expf(de * Aen[6]); hs[6] = fmaf(a, hs[6], B1.z * dexc);
                a = __expf(de * Aen[7]); hs[7] = fmaf(a, hs[7], B1.w * dexc);
            }
            const size_t idx = (((size_t)b * NC + c) * ED + e) * NST + n0;
            *(float4*)(hloc + idx)     = make_float4(hs[0], hs[1], hs[2], hs[3]);
            *(float4*)(hloc + idx + 4) = make_float4(hs[4], hs[5], hs[6], hs[7]);
            *(float4*)(aprod + idx) =
                make_float4(__expf(Aen[0] * dsum), __expf(Aen[1] * dsum),
                            __expf(Aen[2] * dsum), __expf(Aen[3] * dsum));
            *(float4*)(aprod + idx + 4) =
                make_float4(__expf(Aen[4] * dsum), __expf(Aen[5] * dsum),
                            __expf(Aen[6] * dsum), __expf(Aen[7] * dsum));
        }
    }
}

// ---------------- K3b: chunk combine. 256 blocks x 64 threads (all 256 CUs).
__global__ __launch_bounds__(64) void k_scan_combine(
    const float* __restrict__ aprod, float* __restrict__ hloc,
    float* __restrict__ hend)
{
    const int t = blockIdx.x * 64 + threadIdx.x;      // 0..16383
    const int b = t >> 12;                            // ED*NST = 4096
    const int en = t & 4095;
    size_t idx = (size_t)b * NC * (ED * NST) + en;
    float h = 0.f;
    #pragma unroll 4
    for (int c = 0; c < NC; ++c) {
        const float a = aprod[idx];
        const float u = hloc[idx];
        hloc[idx] = h;                 // initial state for chunk c
        h = fmaf(a, h, u);
        idx += ED * NST;
    }
    hend[(size_t)b * (ED * NST) + en] = h;
}

// ---------------- K_C (layers 1..3): scan(y in LDS) + outproj + residual + rms + inproj
__global__ __launch_bounds__(256) void k_scan_gemm(
    const float* __restrict__ delta, const float* __restrict__ Bv,
    const float* __restrict__ Cv, const float* __restrict__ xc,
    const float* __restrict__ zbin, const float* __restrict__ A_log,
    const float* __restrict__ Dp, const float* __restrict__ hinit,
    const float* __restrict__ ow, const float* __restrict__ ob,
    const float* __restrict__ hin, const float* __restrict__ norm_w,
    const float* __restrict__ in_w, const float* __restrict__ in_b,
    float* __restrict__ hout, float* __restrict__ xin, float* __restrict__ zb)
{
    const int blk = blockIdx.x;             // BSZ * NC = 1024
    const int b   = blk >> 8;
    const int c   = blk & 255;
    const int l0  = c * TT;
    const size_t t0 = (size_t)b * Lseq + l0;
    const int tid = threadIdx.x;
    const int e = tid & 127, half = tid >> 7;

    __shared__ __align__(16) float dlS[TT][ED];       // 4 KB
    __shared__ __align__(16) float xcS[TT][ED];       // 4 KB
    __shared__ __align__(16) float BsS[TT][NST];      // 1 KB
    __shared__ __align__(16) float CsS[TT][NST];      // 1 KB
    __shared__ __align__(16) float ys[TT][ED];        // 4 KB
    __shared__ __align__(16) float pp[2][TT][ED];     // 8 KB
    __shared__ __align__(16) float hn[TT][DM];        // 2 KB

    // hoisted Aen (overlap with staging)
    float Aen16[16];
    {
        const float4* a4 = (const float4*)(A_log + e * NST + half * 16);
        #pragma unroll
        for (int i = 0; i < 4; ++i) {
            float4 v = a4[i];
            Aen16[i*4+0] = -__expf(v.x); Aen16[i*4+1] = -__expf(v.y);
            Aen16[i*4+2] = -__expf(v.z); Aen16[i*4+3] = -__expf(v.w);
        }
    }

    {   // stage chunk data (TT*ED/4 = 256 float4 -> one per thread)
        ((float4*)&dlS[0][0])[tid] = ((const float4*)(delta + t0 * ED))[tid];
        ((float4*)&xcS[0][0])[tid] = ((const float4*)(xc + t0 * ED))[tid];
        if (tid < TT * NST / 4) {          // 64
            ((float4*)&BsS[0][0])[tid] = ((const float4*)(Bv + t0 * NST))[tid];
            ((float4*)&CsS[0][0])[tid] = ((const float4*)(Cv + t0 * NST))[tid];
        }
    }
    __syncthreads();

    #pragma unroll 1
    for (int g = 0; g < 2; ++g) {
        const int n0 = half * 16 + g * 8;
        float Aen[8];
        #pragma unroll
        for (int k = 0; k < 8; ++k) Aen[k] = Aen16[g * 8 + k];
        float hs[8];
        {
            const size_t idx = (((size_t)b * NC + c) * ED + e) * NST + n0;
            const float4 h0 = *(const float4*)(hinit + idx);
            const float4 h1 = *(const float4*)(hinit + idx + 4);
            hs[0] = h0.x; hs[1] = h0.y; hs[2] = h0.z; hs[3] = h0.w;
            hs[4] = h1.x; hs[5] = h1.y; hs[6] = h1.z; hs[7] = h1.w;
        }
        #pragma unroll 2
        for (int l = 0; l < TT; ++l) {
            const float de   = dlS[l][e];
            const float dexc = de * xcS[l][e];
            const float4 B0 = *(const float4*)&BsS[l][n0];
            const float4 B1 = *(const float4*)&BsS[l][n0 + 4];
            const float4 C0 = *(const float4*)&CsS[l][n0];
            const float4 C1 = *(const float4*)&CsS[l][n0 + 4];
            float a, p = 0.f;
            a = __expf(de * Aen[0]); hs[0] = fmaf(a, hs[0], B0.x * dexc); p = fmaf(hs[0], C0.x, p);
            a = __expf(de * Aen[1]); hs[1] = fmaf(a, hs[1], B0.y * dexc); p = fmaf(hs[1], C0.y, p);
            a = __expf(de * Aen[2]); hs[2] = fmaf(a, hs[2], B0.z * dexc); p = fmaf(hs[2], C0.z, p);
            a = __expf(de * Aen[3]); hs[3] = fmaf(a, hs[3], B0.w * dexc); p = fmaf(hs[3], C0.w, p);
            a = __expf(de * Aen[4]); hs[4] = fmaf(a, hs[4], B1.x * dexc); p = fmaf(hs[4], C1.x, p);
            a = __expf(de * Aen[5]); hs[5] = fmaf(a, hs[5], B1.y * dexc); p = fmaf(hs[5], C1.y, p);
            a = __expf(de * Aen[6]); hs[6] = fmaf(a, hs[6], B1.z * dexc); p = fmaf(hs[6], C1.z, p);
            a = __expf(de * Aen[7]); hs[7] = fmaf(a, hs[7], B1.w * dexc); p = fmaf(hs[7], C1.w, p);
            if (g == 0) pp[half][l][e] = p;
            else        pp[half][l][e] += p;
        }
    }
    __syncthreads();
    {   // finalize y: 4 tokens per (e,half)
        const float dpe = Dp[e];
        #pragma unroll 2
        for (int j = 0; j < 4; ++j) {
            const int tl = half * 4 + j;
            const size_t tok = t0 + tl;
            const float p = pp[0][tl][e] + pp[1][tl][e];
            const float zi = zbin[tok * ED + e];
            ys[tl][e] = (p + dpe * xcS[tl][e]) * (zi * sigf(zi));
        }
    }
    __syncthreads();

    const int lane = tid & 63;
    const int wv = tid >> 6;
    const float nw = norm_w[lane];
    float hval[2];
    {
        float4 acc[2];
        #pragma unroll
        for (int j = 0; j < 2; ++j) acc[j] = make_float4(0.f, 0.f, 0.f, 0.f);
        #pragma unroll 1
        for (int p = 0; p < 4; ++p) {
            float4 w4[8];
            const float4* wr = (const float4*)(ow + lane * ED + p * 32);
            #pragma unroll
            for (int q = 0; q < 8; ++q) w4[q] = wr[q];
            #pragma unroll
            for (int j = 0; j < 2; ++j) {
                const float4* yv = (const float4*)&ys[wv * 2 + j][p * 32];
                #pragma unroll
                for (int q = 0; q < 8; ++q) {
                    float4 hv = yv[q];
                    acc[j].x = fmaf(hv.x, w4[q].x, acc[j].x);
                    acc[j].y = fmaf(hv.y, w4[q].y, acc[j].y);
                    acc[j].z = fmaf(hv.z, w4[q].z, acc[j].z);
                    acc[j].w = fmaf(hv.w, w4[q].w, acc[j].w);
                }
            }
        }
        const float obd = ob[lane];
        #pragma unroll
        for (int j = 0; j < 2; ++j) {
            const size_t tok = t0 + wv * 2 + j;
            hval[j] = hsum4(acc[j]) + obd + hin[tok * DM + lane];
            hout[tok * DM + lane] = hval[j];
        }
    }
    #pragma unroll
    for (int j = 0; j < 2; ++j) {
        float ss = hval[j] * hval[j];
        #pragma unroll
        for (int off = 32; off; off >>= 1) ss += __shfl_xor(ss, off, 64);
        const float sc = rsqrtf(ss * (1.0f / DM) + EPSV);
        hn[wv * 2 + j][lane] = hval[j] * sc * nw;
    }
    __syncthreads();
    inprojT(in_w, in_b, (const float (*)[DM])hn, xin, zb, t0, tid);
}

// ---------------- K5: last layer head: y(L-1) from hend, then fc dot -> logits
__global__ __launch_bounds__(128) void k_final_last(
    const float* __restrict__ hend, const float* __restrict__ Cv,
    const float* __restrict__ xc, const float* __restrict__ zb,
    const float* __restrict__ Dp, const float* __restrict__ fcw,
    const float* __restrict__ fcb, float* __restrict__ out)
{
    const int b = blockIdx.x;
    const int e = threadIdx.x;
    const size_t tok = (size_t)b * Lseq + (Lseq - 1);
    const float* hp = hend + (size_t)b * (ED * NST) + e * NST;
    const float* cp = Cv + tok * NST;
    float p = 0.f;
    #pragma unroll
    for (int n = 0; n < NST; ++n) p = fmaf(hp[n], cp[n], p);
    const float xce = xc[tok * ED + e];
    const float zi  = zb[tok * ED + e];
    float val = (p + Dp[e] * xce) * (zi * sigf(zi)) * fcw[e];
    __shared__ float sred[2];
    #pragma unroll
    for (int off = 32; off; off >>= 1) val += __shfl_xor(val, off, 64);
    if ((threadIdx.x & 63) == 0) sred[threadIdx.x >> 6] = val;
    __syncthreads();
    if (threadIdx.x == 0) out[b] = sred[0] + sred[1] + fcb[0];
}

extern "C" void kernel_launch(void* const* d_in, const int* in_sizes, int n_in,
                              void* d_out, int out_size, void* d_ws, size_t ws_size,
                              hipStream_t stream)
{
    const float* x         = (const float*)d_in[0];
    const float* in_w      = (const float*)d_in[1];
    const float* in_b      = (const float*)d_in[2];
    const float* conv_w    = (const float*)d_in[3];
    const float* conv_b    = (const float*)d_in[4];
    const float* xproj_w   = (const float*)d_in[5];
    const float* dtproj_w  = (const float*)d_in[6];
    const float* dtproj_b  = (const float*)d_in[7];
    const float* A_log     = (const float*)d_in[8];
    const float* Dp        = (const float*)d_in[9];
    const float* outproj_w = (const float*)d_in[10];
    const float* outproj_b = (const float*)d_in[11];
    const float* norm_w    = (const float*)d_in[12];
    const float* fc_w      = (const float*)d_in[13];
    const float* fc_b      = (const float*)d_in[14];

    const size_t TOK = (size_t)BSZ * Lseq;
    float* ws = (float*)d_ws;
    float* h0    = ws; ws += TOK * DM;
    float* h1    = ws; ws += TOK * DM;
    float* xin   = ws; ws += TOK * ED;
    float* zbuf  = ws; ws += TOK * ED;
    float* xc    = ws; ws += TOK * ED;
    float* dlt   = ws; ws += TOK * ED;
    float* Bv    = ws; ws += TOK * NST;
    float* Cv    = ws; ws += TOK * NST;
    float* aprod = ws; ws += (size_t)BSZ * NC * ED * NST;   // 16 MB
    float* hloc  = ws; ws += (size_t)BSZ * NC * ED * NST;   // 16 MB, becomes hinit
    float* hend  = ws; ws += (size_t)BSZ * ED * NST;

    const float* hres = x;
    float* hbufs[2] = { h0, h1 };

    k_layer_gemm<<<(int)(TOK / TT), 256, 0, stream>>>(
        x, norm_w, in_w, in_b, xin, zbuf);

    for (int i = 0; i < NLAYERS; ++i) {
        const int last = (i == NLAYERS - 1);
        const float* Alog_i = A_log + (size_t)i * ED * NST;
        k_conv_scan<<<(int)(BSZ * NC), 256, 0, stream>>>(
            xin, conv_w + (size_t)i * ED * DCONVK, conv_b + (size_t)i * ED,
            xproj_w + (size_t)i * (DTRANK + 2 * NST) * ED,
            dtproj_w + (size_t)i * ED * DTRANK, dtproj_b + (size_t)i * ED,
            Alog_i, xc, dlt, Bv, Cv, aprod, hloc);
        k_scan_combine<<<(BSZ * ED * NST) / 64, 64, 0, stream>>>(
            aprod, hloc, hend);
        if (!last) {
            float* hout = hbufs[i & 1];
            k_scan_gemm<<<(int)(BSZ * NC), 256, 0, stream>>>(
                dlt, Bv, Cv, xc, zbuf, Alog_i, Dp + (size_t)i * ED, hloc,
                outproj_w + (size_t)i * DM * ED, outproj_b + (size_t)i * DM,
                hres, norm_w + (size_t)(i + 1) * DM,
                in_w + (size_t)(i + 1) * 2 * ED * DM,
                in_b + (size_t)(i + 1) * 2 * ED,
                hout, xin, zbuf);
            hres = hout;
        } else {
            k_final_last<<<BSZ, 128, 0, stream>>>(
                hend, Cv, xc, zbuf, Dp + (size_t)i * ED, fc_w, fc_b, (float*)d_out);
        }
    }
}

// Round 18
// 379.392 us; speedup vs baseline: 1.2475x; 1.2475x over previous
//
#include <hip/hip_runtime.h>
#include <math.h>

#define BSZ 4
#define Lseq 2048
#define DM 64
#define ED 128
#define NST 32
#define DCONVK 16
#define NLAYERS 4
#define DTRANK 4
#define EPSV 1e-5f
#define NC 128                // chunks along L (chunk == conv tile == gemm tile)
#define TT 16                 // tokens per block (R17's TT=8 regressed; 16 is the sweet spot)

__device__ __forceinline__ float sigf(float x) { return 1.0f / (1.0f + __expf(-x)); }
__device__ __forceinline__ float hsum4(float4 a) { return (a.x + a.y) + (a.z + a.w); }

// inproj: 64 -> 256 for 16 tokens; hn in LDS; writes xin (tid<128) / zbuf.
__device__ __forceinline__ void inproj16(
    const float* in_w_l, const float* in_b_l, const float (*hn)[DM],
    float* xin, float* zbuf, size_t t0, int tid)
{
    float4 w4[16];
    const float4* wr = (const float4*)(in_w_l + tid * DM);
    #pragma unroll
    for (int i = 0; i < 16; ++i) w4[i] = wr[i];
    const float bias = in_b_l[tid];
    #pragma unroll 2
    for (int tok = 0; tok < TT; ++tok) {
        const float4* hv4 = (const float4*)&hn[tok][0];
        float4 a4 = make_float4(0.f, 0.f, 0.f, 0.f);
        #pragma unroll
        for (int i = 0; i < 16; ++i) {
            float4 hv = hv4[i];
            a4.x = fmaf(hv.x, w4[i].x, a4.x);
            a4.y = fmaf(hv.y, w4[i].y, a4.y);
            a4.z = fmaf(hv.z, w4[i].z, a4.z);
            a4.w = fmaf(hv.w, w4[i].w, a4.w);
        }
        const float r = bias + hsum4(a4);
        if (tid < ED) xin[(t0 + tok) * ED + tid] = r;
        else          zbuf[(t0 + tok) * ED + (tid - ED)] = r;
    }
}

// ---------------- K_A (layer 0 only): rmsnorm + inproj, 16 tokens/block
__global__ __launch_bounds__(256) void k_layer_gemm(
    const float* __restrict__ hin, const float* __restrict__ norm_w,
    const float* __restrict__ in_w, const float* __restrict__ in_b,
    float* __restrict__ xin, float* __restrict__ zb)
{
    const int t0 = blockIdx.x * TT;
    const int tid = threadIdx.x;
    const int lane = tid & 63;
    const int wv = tid >> 6;
    __shared__ __align__(16) float hn[TT][DM];

    const float nw = norm_w[lane];
    float hval[4];
    #pragma unroll
    for (int j = 0; j < 4; ++j)
        hval[j] = hin[(size_t)(t0 + wv * 4 + j) * DM + lane];

    #pragma unroll
    for (int j = 0; j < 4; ++j) {
        float ss = hval[j] * hval[j];
        #pragma unroll
        for (int off = 32; off; off >>= 1) ss += __shfl_xor(ss, off, 64);
        const float sc = rsqrtf(ss * (1.0f / DM) + EPSV);
        hn[wv * 4 + j][lane] = hval[j] * sc * nw;
    }
    __syncthreads();
    inproj16(in_w, in_b, (const float (*)[DM])hn, xin, zb, (size_t)t0, tid);
}

// ---------------- K_B: conv + silu + xproj + dtproj + local scan — 1 chunk/block
// store_dbc==0 (last layer): skip dead delta_out/Bout global stores.
__global__ __launch_bounds__(256) void k_conv_scan(
    const float* __restrict__ xin, const float* __restrict__ conv_w,
    const float* __restrict__ conv_b, const float* __restrict__ xproj_w,
    const float* __restrict__ dtproj_w, const float* __restrict__ dtproj_b,
    const float* __restrict__ A_log,
    float* __restrict__ xc_out, float* __restrict__ delta_out,
    float* __restrict__ Bout, float* __restrict__ Cout,
    float* __restrict__ aprod, float* __restrict__ hloc, int store_dbc)
{
    const int blk = blockIdx.x;             // BSZ * NC = 512 blocks
    const int b   = blk >> 7;               // NC = 128
    const int c   = blk & 127;
    const int l0  = c * TT;
    const size_t t0 = (size_t)b * Lseq + l0;
    const int tid = threadIdx.x;
    const int e = tid & 127, half = tid >> 7;
    __shared__ __align__(16) float xs[(TT + DCONVK - 1) * ED];   // 31 rows, 15.5 KB
    __shared__ __align__(16) float xcs[TT][ED];                   // 8 KB
    __shared__ __align__(16) float Bs[TT][NST];                   // 2 KB
    __shared__ float dts[TT][DTRANK];
    float (*dl)[ED] = (float (*)[ED])xs;    // alias: xs dead after conv phase

    // hoisted global loads (overlap with staging)
    float Aen16[16];
    {
        const float4* a4 = (const float4*)(A_log + e * NST + half * 16);
        #pragma unroll
        for (int i = 0; i < 4; ++i) {
            float4 v = a4[i];
            Aen16[i*4+0] = -__expf(v.x); Aen16[i*4+1] = -__expf(v.y);
            Aen16[i*4+2] = -__expf(v.z); Aen16[i*4+3] = -__expf(v.w);
        }
    }
    float w[DCONVK];
    {
        const float4* cw = (const float4*)(conv_w + e * DCONVK);
        #pragma unroll
        for (int i = 0; i < 4; ++i) {
            float4 cc = cw[i];
            w[i*4+0] = cc.x; w[i*4+1] = cc.y; w[i*4+2] = cc.z; w[i*4+3] = cc.w;
        }
    }
    const float cb = conv_b[e];

    {
        const int NV = (TT + DCONVK - 1) * ED / 4;   // 992
        for (int idx4 = tid; idx4 < NV; idx4 += 256) {
            const int row = idx4 >> 5;
            const int lrow = l0 - (DCONVK - 1) + row;
            float4 v = make_float4(0.f, 0.f, 0.f, 0.f);
            if (lrow >= 0)
                v = ((const float4*)(xin + ((size_t)b * Lseq + lrow) * ED))[idx4 & 31];
            ((float4*)xs)[idx4] = v;
        }
    }
    __syncthreads();

    {   // conv + silu
        #pragma unroll 2
        for (int j = 0; j < 8; ++j) {
            const int tok = half * 8 + j;
            float acc = cb;
            #pragma unroll
            for (int k = 0; k < DCONVK; ++k)
                acc = fmaf(xs[(tok + k) * ED + e], w[k], acc);
            const float xcv = acc * sigf(acc);
            xcs[tok][e] = xcv;
            xc_out[(t0 + tok) * ED + e] = xcv;
        }
    }
    __syncthreads();   // xs dead from here on

    {   // xproj: 4 passes of w4[8], acc[4]
        const int wv = tid >> 6, lane = tid & 63;
        float4 acc[4];
        #pragma unroll
        for (int j = 0; j < 4; ++j) acc[j] = make_float4(0.f, 0.f, 0.f, 0.f);
        #pragma unroll 1
        for (int p = 0; p < 4; ++p) {
            float4 w4[8];
            const float4* wr = (const float4*)(xproj_w + lane * ED + p * 32);
            #pragma unroll
            for (int i = 0; i < 8; ++i) w4[i] = wr[i];
            #pragma unroll
            for (int j = 0; j < 4; ++j) {
                const float4* yv = (const float4*)&xcs[wv * 4 + j][p * 32];
                #pragma unroll
                for (int i = 0; i < 8; ++i) {
                    float4 hv = yv[i];
                    acc[j].x = fmaf(hv.x, w4[i].x, acc[j].x);
                    acc[j].y = fmaf(hv.y, w4[i].y, acc[j].y);
                    acc[j].z = fmaf(hv.z, w4[i].z, acc[j].z);
                    acc[j].w = fmaf(hv.w, w4[i].w, acc[j].w);
                }
            }
        }
        #pragma unroll
        for (int j = 0; j < 4; ++j) {
            const int tok = wv * 4 + j;
            const float v = hsum4(acc[j]);
            if (lane < DTRANK) {
                dts[tok][lane] = v;
            } else if (lane < DTRANK + NST) {
                Bs[tok][lane - DTRANK] = v;
                if (store_dbc) Bout[(t0 + tok) * NST + (lane - DTRANK)] = v;
            } else {
                Cout[(t0 + tok) * NST + (lane - DTRANK - NST)] = v;
            }
        }
        {
            const int ridx = lane & 3;
            const int ks   = (lane >> 2) & 3;
            const int tsub = lane >> 4;
            const int r4   = 64 + ridx;
            const int tok  = wv * 4 + tsub;
            const float4* wr = (const float4*)(xproj_w + r4 * ED + ks * 32);
            const float4* yv = (const float4*)&xcs[tok][ks * 32];
            float4 a4 = make_float4(0.f, 0.f, 0.f, 0.f);
            #pragma unroll
            for (int i = 0; i < 8; ++i) {
                float4 hv = yv[i]; float4 wv4 = wr[i];
                a4.x = fmaf(hv.x, wv4.x, a4.x);
                a4.y = fmaf(hv.y, wv4.y, a4.y);
                a4.z = fmaf(hv.z, wv4.z, a4.z);
                a4.w = fmaf(hv.w, wv4.w, a4.w);
            }
            float v = hsum4(a4);
            v += __shfl_xor(v, 4, 64);
            v += __shfl_xor(v, 8, 64);
            if (ks == 0) Cout[(t0 + tok) * NST + (r4 - DTRANK - NST)] = v;
        }
    }
    __syncthreads();

    {   // dtproj + softplus -> dl (aliased LDS) + delta_out
        const float4 dwv = *(const float4*)(dtproj_w + e * DTRANK);
        const float bias = dtproj_b[e];
        #pragma unroll 2
        for (int j = 0; j < 8; ++j) {
            const int tok = half * 8 + j;
            float a = bias;
            a = fmaf(dts[tok][0], dwv.x, a);
            a = fmaf(dts[tok][1], dwv.y, a);
            a = fmaf(dts[tok][2], dwv.z, a);
            a = fmaf(dts[tok][3], dwv.w, a);
            const float sp = fmaxf(a, 0.f) + log1pf(__expf(-fabsf(a)));
            dl[tok][e] = sp;
            if (store_dbc) delta_out[(t0 + tok) * ED + e] = sp;
        }
    }
    __syncthreads();

    {   // local scan: two 8-state passes (unroll 2), Aen from hoisted regs
        float dsum = 0.f;
        #pragma unroll 4
        for (int l = 0; l < TT; ++l) dsum += dl[l][e];

        #pragma unroll 1
        for (int g = 0; g < 2; ++g) {
            const int n0 = half * 16 + g * 8;
            float Aen[8];
            #pragma unroll
            for (int k = 0; k < 8; ++k) Aen[k] = Aen16[g * 8 + k];
            float hs[8];
            #pragma unroll
            for (int k = 0; k < 8; ++k) hs[k] = 0.f;
            #pragma unroll 2
            for (int l = 0; l < TT; ++l) {
                const float de   = dl[l][e];
                const float dexc = de * xcs[l][e];
                const float4 B0 = *(const float4*)&Bs[l][n0];
                const float4 B1 = *(const float4*)&Bs[l][n0 + 4];
                float a;
                a = __expf(de * Aen[0]); hs[0] = fmaf(a, hs[0], B0.x * dexc);
                a = __expf(de * Aen[1]); hs[1] = fmaf(a, hs[1], B0.y * dexc);
                a = __expf(de * Aen[2]); hs[2] = fmaf(a, hs[2], B0.z * dexc);
                a = __expf(de * Aen[3]); hs[3] = fmaf(a, hs[3], B0.w * dexc);
                a = __expf(de * Aen[4]); hs[4] = fmaf(a, hs[4], B1.x * dexc);
                a = __expf(de * Aen[5]); hs[5] = fmaf(a, hs[5], B1.y * dexc);
                a = __expf(de * Aen[6]); hs[6] = fmaf(a, hs[6], B1.z * dexc);
                a = __expf(de * Aen[7]); hs[7] = fmaf(a, hs[7], B1.w * dexc);
            }
            const size_t idx = (((size_t)b * NC + c) * ED + e) * NST + n0;
            *(float4*)(hloc + idx)     = make_float4(hs[0], hs[1], hs[2], hs[3]);
            *(float4*)(hloc + idx + 4) = make_float4(hs[4], hs[5], hs[6], hs[7]);
            *(float4*)(aprod + idx) =
                make_float4(__expf(Aen[0] * dsum), __expf(Aen[1] * dsum),
                            __expf(Aen[2] * dsum), __expf(Aen[3] * dsum));
            *(float4*)(aprod + idx + 4) =
                make_float4(__expf(Aen[4] * dsum), __expf(Aen[5] * dsum),
                            __expf(Aen[6] * dsum), __expf(Aen[7] * dsum));
        }
    }
}

// ---------------- K3b: chunk combine. 256 blocks x 64 threads (all 256 CUs).
// want_hend: hend only consumed by the last layer's head.
__global__ __launch_bounds__(64) void k_scan_combine(
    const float* __restrict__ aprod, float* __restrict__ hloc,
    float* __restrict__ hend, int want_hend)
{
    const int t = blockIdx.x * 64 + threadIdx.x;      // 0..16383
    const int b = t >> 12;                            // ED*NST = 4096
    const int en = t & 4095;
    size_t idx = (size_t)b * NC * (ED * NST) + en;
    float h = 0.f;
    #pragma unroll 4
    for (int c = 0; c < NC; ++c) {
        const float a = aprod[idx];
        const float u = hloc[idx];
        hloc[idx] = h;                 // initial state for chunk c
        h = fmaf(a, h, u);
        idx += ED * NST;
    }
    if (want_hend) hend[(size_t)b * (ED * NST) + en] = h;
}

// ---------------- K_C (layers 1..3): scan(y in LDS) + outproj + residual + rms + inproj
__global__ __launch_bounds__(256) void k_scan_gemm(
    const float* __restrict__ delta, const float* __restrict__ Bv,
    const float* __restrict__ Cv, const float* __restrict__ xc,
    const float* __restrict__ zbin, const float* __restrict__ A_log,
    const float* __restrict__ Dp, const float* __restrict__ hinit,
    const float* __restrict__ ow, const float* __restrict__ ob,
    const float* __restrict__ hin, const float* __restrict__ norm_w,
    const float* __restrict__ in_w, const float* __restrict__ in_b,
    float* __restrict__ hout, float* __restrict__ xin, float* __restrict__ zb)
{
    const int blk = blockIdx.x;             // BSZ * NC = 512
    const int b   = blk >> 7;
    const int c   = blk & 127;
    const int l0  = c * TT;
    const size_t t0 = (size_t)b * Lseq + l0;
    const int tid = threadIdx.x;
    const int e = tid & 127, half = tid >> 7;

    __shared__ __align__(16) float dlS[TT][ED];
    __shared__ __align__(16) float xcS[TT][ED];
    __shared__ __align__(16) float BsS[TT][NST];
    __shared__ __align__(16) float CsS[TT][NST];
    __shared__ __align__(16) float ys[TT][ED];
    __shared__ __align__(16) float pp[2][TT][ED];
    __shared__ __align__(16) float hn[TT][DM];

    // hoisted Aen (overlap with staging)
    float Aen16[16];
    {
        const float4* a4 = (const float4*)(A_log + e * NST + half * 16);
        #pragma unroll
        for (int i = 0; i < 4; ++i) {
            float4 v = a4[i];
            Aen16[i*4+0] = -__expf(v.x); Aen16[i*4+1] = -__expf(v.y);
            Aen16[i*4+2] = -__expf(v.z); Aen16[i*4+3] = -__expf(v.w);
        }
    }

    {
        const float4* dsrc = (const float4*)(delta + t0 * ED);
        const float4* xsrc = (const float4*)(xc + t0 * ED);
        float4* ddst = (float4*)&dlS[0][0];
        float4* xdst = (float4*)&xcS[0][0];
        #pragma unroll
        for (int i = 0; i < 2; ++i) {
            ddst[tid + i * 256] = dsrc[tid + i * 256];
            xdst[tid + i * 256] = xsrc[tid + i * 256];
        }
        if (tid < 128) {
            ((float4*)&BsS[0][0])[tid] = ((const float4*)(Bv + t0 * NST))[tid];
            ((float4*)&CsS[0][0])[tid] = ((const float4*)(Cv + t0 * NST))[tid];
        }
    }
    __syncthreads();

    #pragma unroll 1
    for (int g = 0; g < 2; ++g) {
        const int n0 = half * 16 + g * 8;
        float Aen[8];
        #pragma unroll
        for (int k = 0; k < 8; ++k) Aen[k] = Aen16[g * 8 + k];
        float hs[8];
        {
            const size_t idx = (((size_t)b * NC + c) * ED + e) * NST + n0;
            const float4 h0 = *(const float4*)(hinit + idx);
            const float4 h1 = *(const float4*)(hinit + idx + 4);
            hs[0] = h0.x; hs[1] = h0.y; hs[2] = h0.z; hs[3] = h0.w;
            hs[4] = h1.x; hs[5] = h1.y; hs[6] = h1.z; hs[7] = h1.w;
        }
        #pragma unroll 2
        for (int l = 0; l < TT; ++l) {
            const float de   = dlS[l][e];
            const float dexc = de * xcS[l][e];
            const float4 B0 = *(const float4*)&BsS[l][n0];
            const float4 B1 = *(const float4*)&BsS[l][n0 + 4];
            const float4 C0 = *(const float4*)&CsS[l][n0];
            const float4 C1 = *(const float4*)&CsS[l][n0 + 4];
            float a, p = 0.f;
            a = __expf(de * Aen[0]); hs[0] = fmaf(a, hs[0], B0.x * dexc); p = fmaf(hs[0], C0.x, p);
            a = __expf(de * Aen[1]); hs[1] = fmaf(a, hs[1], B0.y * dexc); p = fmaf(hs[1], C0.y, p);
            a = __expf(de * Aen[2]); hs[2] = fmaf(a, hs[2], B0.z * dexc); p = fmaf(hs[2], C0.z, p);
            a = __expf(de * Aen[3]); hs[3] = fmaf(a, hs[3], B0.w * dexc); p = fmaf(hs[3], C0.w, p);
            a = __expf(de * Aen[4]); hs[4] = fmaf(a, hs[4], B1.x * dexc); p = fmaf(hs[4], C1.x, p);
            a = __expf(de * Aen[5]); hs[5] = fmaf(a, hs[5], B1.y * dexc); p = fmaf(hs[5], C1.y, p);
            a = __expf(de * Aen[6]); hs[6] = fmaf(a, hs[6], B1.z * dexc); p = fmaf(hs[6], C1.z, p);
            a = __expf(de * Aen[7]); hs[7] = fmaf(a, hs[7], B1.w * dexc); p = fmaf(hs[7], C1.w, p);
            if (g == 0) pp[half][l][e] = p;
            else        pp[half][l][e] += p;
        }
    }
    __syncthreads();
    {
        const float dpe = Dp[e];
        #pragma unroll 2
        for (int j = 0; j < 8; ++j) {
            const int tl = half * 8 + j;
            const size_t tok = t0 + tl;
            const float p = pp[0][tl][e] + pp[1][tl][e];
            const float zi = zbin[tok * ED + e];
            ys[tl][e] = (p + dpe * xcS[tl][e]) * (zi * sigf(zi));
        }
    }
    __syncthreads();

    const int lane = tid & 63;
    const int wv = tid >> 6;
    const float nw = norm_w[lane];
    float hval[4];
    {
        float4 acc[4];
        #pragma unroll
        for (int j = 0; j < 4; ++j) acc[j] = make_float4(0.f, 0.f, 0.f, 0.f);
        #pragma unroll 1
        for (int p = 0; p < 4; ++p) {
            float4 w4[8];
            const float4* wr = (const float4*)(ow + lane * ED + p * 32);
            #pragma unroll
            for (int q = 0; q < 8; ++q) w4[q] = wr[q];
            #pragma unroll
            for (int j = 0; j < 4; ++j) {
                const float4* yv = (const float4*)&ys[wv * 4 + j][p * 32];
                #pragma unroll
                for (int q = 0; q < 8; ++q) {
                    float4 hv = yv[q];
                    acc[j].x = fmaf(hv.x, w4[q].x, acc[j].x);
                    acc[j].y = fmaf(hv.y, w4[q].y, acc[j].y);
                    acc[j].z = fmaf(hv.z, w4[q].z, acc[j].z);
                    acc[j].w = fmaf(hv.w, w4[q].w, acc[j].w);
                }
            }
        }
        const float obd = ob[lane];
        #pragma unroll
        for (int j = 0; j < 4; ++j) {
            const size_t tok = t0 + wv * 4 + j;
            hval[j] = hsum4(acc[j]) + obd + hin[tok * DM + lane];
            hout[tok * DM + lane] = hval[j];
        }
    }
    #pragma unroll
    for (int j = 0; j < 4; ++j) {
        float ss = hval[j] * hval[j];
        #pragma unroll
        for (int off = 32; off; off >>= 1) ss += __shfl_xor(ss, off, 64);
        const float sc = rsqrtf(ss * (1.0f / DM) + EPSV);
        hn[wv * 4 + j][lane] = hval[j] * sc * nw;
    }
    __syncthreads();
    inproj16(in_w, in_b, (const float (*)[DM])hn, xin, zb, t0, tid);
}

// ---------------- K5: last layer head: y(L-1) from hend, then fc dot -> logits
__global__ __launch_bounds__(128) void k_final_last(
    const float* __restrict__ hend, const float* __restrict__ Cv,
    const float* __restrict__ xc, const float* __restrict__ zb,
    const float* __restrict__ Dp, const float* __restrict__ fcw,
    const float* __restrict__ fcb, float* __restrict__ out)
{
    const int b = blockIdx.x;
    const int e = threadIdx.x;
    const size_t tok = (size_t)b * Lseq + (Lseq - 1);
    const float* hp = hend + (size_t)b * (ED * NST) + e * NST;
    const float* cp = Cv + tok * NST;
    float p = 0.f;
    #pragma unroll
    for (int n = 0; n < NST; ++n) p = fmaf(hp[n], cp[n], p);
    const float xce = xc[tok * ED + e];
    const float zi  = zb[tok * ED + e];
    float val = (p + Dp[e] * xce) * (zi * sigf(zi)) * fcw[e];
    __shared__ float sred[2];
    #pragma unroll
    for (int off = 32; off; off >>= 1) val += __shfl_xor(val, off, 64);
    if ((threadIdx.x & 63) == 0) sred[threadIdx.x >> 6] = val;
    __syncthreads();
    if (threadIdx.x == 0) out[b] = sred[0] + sred[1] + fcb[0];
}

extern "C" void kernel_launch(void* const* d_in, const int* in_sizes, int n_in,
                              void* d_out, int out_size, void* d_ws, size_t ws_size,
                              hipStream_t stream)
{
    const float* x         = (const float*)d_in[0];
    const float* in_w      = (const float*)d_in[1];
    const float* in_b      = (const float*)d_in[2];
    const float* conv_w    = (const float*)d_in[3];
    const float* conv_b    = (const float*)d_in[4];
    const float* xproj_w   = (const float*)d_in[5];
    const float* dtproj_w  = (const float*)d_in[6];
    const float* dtproj_b  = (const float*)d_in[7];
    const float* A_log     = (const float*)d_in[8];
    const float* Dp        = (const float*)d_in[9];
    const float* outproj_w = (const float*)d_in[10];
    const float* outproj_b = (const float*)d_in[11];
    const float* norm_w    = (const float*)d_in[12];
    const float* fc_w      = (const float*)d_in[13];
    const float* fc_b      = (const float*)d_in[14];

    const size_t TOK = (size_t)BSZ * Lseq;
    float* ws = (float*)d_ws;
    float* h0    = ws; ws += TOK * DM;
    float* h1    = ws; ws += TOK * DM;
    float* xin   = ws; ws += TOK * ED;
    float* zbuf  = ws; ws += TOK * ED;
    float* xc    = ws; ws += TOK * ED;
    float* dlt   = ws; ws += TOK * ED;
    float* Bv    = ws; ws += TOK * NST;
    float* Cv    = ws; ws += TOK * NST;
    float* aprod = ws; ws += (size_t)BSZ * NC * ED * NST;   // 8 MB
    float* hloc  = ws; ws += (size_t)BSZ * NC * ED * NST;   // 8 MB, becomes hinit
    float* hend  = ws; ws += (size_t)BSZ * ED * NST;

    const float* hres = x;
    float* hbufs[2] = { h0, h1 };

    k_layer_gemm<<<(int)(TOK / TT), 256, 0, stream>>>(
        x, norm_w, in_w, in_b, xin, zbuf);

    for (int i = 0; i < NLAYERS; ++i) {
        const int last = (i == NLAYERS - 1);
        const float* Alog_i = A_log + (size_t)i * ED * NST;
        k_conv_scan<<<(int)(BSZ * NC), 256, 0, stream>>>(
            xin, conv_w + (size_t)i * ED * DCONVK, conv_b + (size_t)i * ED,
            xproj_w + (size_t)i * (DTRANK + 2 * NST) * ED,
            dtproj_w + (size_t)i * ED * DTRANK, dtproj_b + (size_t)i * ED,
            Alog_i, xc, dlt, Bv, Cv, aprod, hloc, last ? 0 : 1);
        k_scan_combine<<<(BSZ * ED * NST) / 64, 64, 0, stream>>>(
            aprod, hloc, hend, last ? 1 : 0);
        if (!last) {
            float* hout = hbufs[i & 1];
            k_scan_gemm<<<(int)(BSZ * NC), 256, 0, stream>>>(
                dlt, Bv, Cv, xc, zbuf, Alog_i, Dp + (size_t)i * ED, hloc,
                outproj_w + (size_t)i * DM * ED, outproj_b + (size_t)i * DM,
                hres, norm_w + (size_t)(i + 1) * DM,
                in_w + (size_t)(i + 1) * 2 * ED * DM,
                in_b + (size_t)(i + 1) * 2 * ED,
                hout, xin, zbuf);
            hres = hout;
        } else {
            k_final_last<<<BSZ, 128, 0, stream>>>(
                hend, Cv, xc, zbuf, Dp + (size_t)i * ED, fc_w, fc_b, (float*)d_out);
        }
    }
}

// Round 19
// 374.750 us; speedup vs baseline: 1.2630x; 1.0124x over previous
//
#include <hip/hip_runtime.h>
#include <math.h>

#define BSZ 4
#define Lseq 2048
#define DM 64
#define ED 128
#define NST 32
#define DCONVK 16
#define NLAYERS 4
#define DTRANK 4
#define EPSV 1e-5f
#define NC 128                // chunks along L (chunk == conv tile == gemm tile)
#define TT 16                 // tokens per block (TT=8 measured worse; 16 is the sweet spot)

__device__ __forceinline__ float sigf(float x) { return 1.0f / (1.0f + __expf(-x)); }
__device__ __forceinline__ float hsum4(float4 a) { return (a.x + a.y) + (a.z + a.w); }

// inproj: 64 -> 256 for 16 tokens; hn in LDS; writes xin (tid<128) / zbuf.
__device__ __forceinline__ void inproj16(
    const float* in_w_l, const float* in_b_l, const float (*hn)[DM],
    float* xin, float* zbuf, size_t t0, int tid)
{
    float4 w4[16];
    const float4* wr = (const float4*)(in_w_l + tid * DM);
    #pragma unroll
    for (int i = 0; i < 16; ++i) w4[i] = wr[i];
    const float bias = in_b_l[tid];
    #pragma unroll 2
    for (int tok = 0; tok < TT; ++tok) {
        const float4* hv4 = (const float4*)&hn[tok][0];
        float4 a4 = make_float4(0.f, 0.f, 0.f, 0.f);
        #pragma unroll
        for (int i = 0; i < 16; ++i) {
            float4 hv = hv4[i];
            a4.x = fmaf(hv.x, w4[i].x, a4.x);
            a4.y = fmaf(hv.y, w4[i].y, a4.y);
            a4.z = fmaf(hv.z, w4[i].z, a4.z);
            a4.w = fmaf(hv.w, w4[i].w, a4.w);
        }
        const float r = bias + hsum4(a4);
        if (tid < ED) xin[(t0 + tok) * ED + tid] = r;
        else          zbuf[(t0 + tok) * ED + (tid - ED)] = r;
    }
}

// ---------------- K_A (layer 0 only): rmsnorm + inproj, 16 tokens/block
// Also zeroes the 4-float logits buffer (consumed via atomicAdd by the fused head).
__global__ __launch_bounds__(256) void k_layer_gemm(
    const float* __restrict__ hin, const float* __restrict__ norm_w,
    const float* __restrict__ in_w, const float* __restrict__ in_b,
    float* __restrict__ xin, float* __restrict__ zb, float* __restrict__ out)
{
    const int t0 = blockIdx.x * TT;
    const int tid = threadIdx.x;
    const int lane = tid & 63;
    const int wv = tid >> 6;
    __shared__ __align__(16) float hn[TT][DM];

    if (blockIdx.x == 0 && tid < BSZ) out[tid] = 0.f;

    const float nw = norm_w[lane];
    float hval[4];
    #pragma unroll
    for (int j = 0; j < 4; ++j)
        hval[j] = hin[(size_t)(t0 + wv * 4 + j) * DM + lane];

    #pragma unroll
    for (int j = 0; j < 4; ++j) {
        float ss = hval[j] * hval[j];
        #pragma unroll
        for (int off = 32; off; off >>= 1) ss += __shfl_xor(ss, off, 64);
        const float sc = rsqrtf(ss * (1.0f / DM) + EPSV);
        hn[wv * 4 + j][lane] = hval[j] * sc * nw;
    }
    __syncthreads();
    inproj16(in_w, in_b, (const float (*)[DM])hn, xin, zb, (size_t)t0, tid);
}

// ---------------- K_B: conv + silu + xproj + dtproj + local scan — 1 chunk/block
// store_dbc==0 (last layer): skip delta/B stores everywhere; xc/C stores only
// from the c==NC-1 block (the head reads token L-1 only).
__global__ __launch_bounds__(256) void k_conv_scan(
    const float* __restrict__ xin, const float* __restrict__ conv_w,
    const float* __restrict__ conv_b, const float* __restrict__ xproj_w,
    const float* __restrict__ dtproj_w, const float* __restrict__ dtproj_b,
    const float* __restrict__ A_log,
    float* __restrict__ xc_out, float* __restrict__ delta_out,
    float* __restrict__ Bout, float* __restrict__ Cout,
    float* __restrict__ aprod, float* __restrict__ hloc, int store_dbc)
{
    const int blk = blockIdx.x;             // BSZ * NC = 512 blocks
    const int b   = blk >> 7;               // NC = 128
    const int c   = blk & 127;
    const int l0  = c * TT;
    const size_t t0 = (size_t)b * Lseq + l0;
    const int tid = threadIdx.x;
    const int e = tid & 127, half = tid >> 7;
    const bool doXC = store_dbc || (c == NC - 1);
    __shared__ __align__(16) float xs[(TT + DCONVK - 1) * ED];   // 31 rows, 15.5 KB
    __shared__ __align__(16) float xcs[TT][ED];                   // 8 KB
    __shared__ __align__(16) float Bs[TT][NST];                   // 2 KB
    __shared__ float dts[TT][DTRANK];
    float (*dl)[ED] = (float (*)[ED])xs;    // alias: xs dead after conv phase

    // hoisted global loads (overlap with staging)
    float Aen16[16];
    {
        const float4* a4 = (const float4*)(A_log + e * NST + half * 16);
        #pragma unroll
        for (int i = 0; i < 4; ++i) {
            float4 v = a4[i];
            Aen16[i*4+0] = -__expf(v.x); Aen16[i*4+1] = -__expf(v.y);
            Aen16[i*4+2] = -__expf(v.z); Aen16[i*4+3] = -__expf(v.w);
        }
    }
    float w[DCONVK];
    {
        const float4* cw = (const float4*)(conv_w + e * DCONVK);
        #pragma unroll
        for (int i = 0; i < 4; ++i) {
            float4 cc = cw[i];
            w[i*4+0] = cc.x; w[i*4+1] = cc.y; w[i*4+2] = cc.z; w[i*4+3] = cc.w;
        }
    }
    const float cb = conv_b[e];

    {
        const int NV = (TT + DCONVK - 1) * ED / 4;   // 992
        for (int idx4 = tid; idx4 < NV; idx4 += 256) {
            const int row = idx4 >> 5;
            const int lrow = l0 - (DCONVK - 1) + row;
            float4 v = make_float4(0.f, 0.f, 0.f, 0.f);
            if (lrow >= 0)
                v = ((const float4*)(xin + ((size_t)b * Lseq + lrow) * ED))[idx4 & 31];
            ((float4*)xs)[idx4] = v;
        }
    }
    __syncthreads();

    {   // conv + silu
        #pragma unroll 2
        for (int j = 0; j < 8; ++j) {
            const int tok = half * 8 + j;
            float acc = cb;
            #pragma unroll
            for (int k = 0; k < DCONVK; ++k)
                acc = fmaf(xs[(tok + k) * ED + e], w[k], acc);
            const float xcv = acc * sigf(acc);
            xcs[tok][e] = xcv;
            if (doXC) xc_out[(t0 + tok) * ED + e] = xcv;
        }
    }
    __syncthreads();   // xs dead from here on

    {   // xproj: 4 passes of w4[8], acc[4]
        const int wv = tid >> 6, lane = tid & 63;
        float4 acc[4];
        #pragma unroll
        for (int j = 0; j < 4; ++j) acc[j] = make_float4(0.f, 0.f, 0.f, 0.f);
        #pragma unroll 1
        for (int p = 0; p < 4; ++p) {
            float4 w4[8];
            const float4* wr = (const float4*)(xproj_w + lane * ED + p * 32);
            #pragma unroll
            for (int i = 0; i < 8; ++i) w4[i] = wr[i];
            #pragma unroll
            for (int j = 0; j < 4; ++j) {
                const float4* yv = (const float4*)&xcs[wv * 4 + j][p * 32];
                #pragma unroll
                for (int i = 0; i < 8; ++i) {
                    float4 hv = yv[i];
                    acc[j].x = fmaf(hv.x, w4[i].x, acc[j].x);
                    acc[j].y = fmaf(hv.y, w4[i].y, acc[j].y);
                    acc[j].z = fmaf(hv.z, w4[i].z, acc[j].z);
                    acc[j].w = fmaf(hv.w, w4[i].w, acc[j].w);
                }
            }
        }
        #pragma unroll
        for (int j = 0; j < 4; ++j) {
            const int tok = wv * 4 + j;
            const float v = hsum4(acc[j]);
            if (lane < DTRANK) {
                dts[tok][lane] = v;
            } else if (lane < DTRANK + NST) {
                Bs[tok][lane - DTRANK] = v;
                if (store_dbc) Bout[(t0 + tok) * NST + (lane - DTRANK)] = v;
            } else {
                if (doXC) Cout[(t0 + tok) * NST + (lane - DTRANK - NST)] = v;
            }
        }
        {
            const int ridx = lane & 3;
            const int ks   = (lane >> 2) & 3;
            const int tsub = lane >> 4;
            const int r4   = 64 + ridx;
            const int tok  = wv * 4 + tsub;
            const float4* wr = (const float4*)(xproj_w + r4 * ED + ks * 32);
            const float4* yv = (const float4*)&xcs[tok][ks * 32];
            float4 a4 = make_float4(0.f, 0.f, 0.f, 0.f);
            #pragma unroll
            for (int i = 0; i < 8; ++i) {
                float4 hv = yv[i]; float4 wv4 = wr[i];
                a4.x = fmaf(hv.x, wv4.x, a4.x);
                a4.y = fmaf(hv.y, wv4.y, a4.y);
                a4.z = fmaf(hv.z, wv4.z, a4.z);
                a4.w = fmaf(hv.w, wv4.w, a4.w);
            }
            float v = hsum4(a4);
            v += __shfl_xor(v, 4, 64);
            v += __shfl_xor(v, 8, 64);
            if (ks == 0 && doXC) Cout[(t0 + tok) * NST + (r4 - DTRANK - NST)] = v;
        }
    }
    __syncthreads();

    {   // dtproj + softplus -> dl (aliased LDS) + delta_out
        const float4 dwv = *(const float4*)(dtproj_w + e * DTRANK);
        const float bias = dtproj_b[e];
        #pragma unroll 2
        for (int j = 0; j < 8; ++j) {
            const int tok = half * 8 + j;
            float a = bias;
            a = fmaf(dts[tok][0], dwv.x, a);
            a = fmaf(dts[tok][1], dwv.y, a);
            a = fmaf(dts[tok][2], dwv.z, a);
            a = fmaf(dts[tok][3], dwv.w, a);
            const float sp = fmaxf(a, 0.f) + log1pf(__expf(-fabsf(a)));
            dl[tok][e] = sp;
            if (store_dbc) delta_out[(t0 + tok) * ED + e] = sp;
        }
    }
    __syncthreads();

    {   // local scan: two 8-state passes (unroll 2), Aen from hoisted regs
        float dsum = 0.f;
        #pragma unroll 4
        for (int l = 0; l < TT; ++l) dsum += dl[l][e];

        #pragma unroll 1
        for (int g = 0; g < 2; ++g) {
            const int n0 = half * 16 + g * 8;
            float Aen[8];
            #pragma unroll
            for (int k = 0; k < 8; ++k) Aen[k] = Aen16[g * 8 + k];
            float hs[8];
            #pragma unroll
            for (int k = 0; k < 8; ++k) hs[k] = 0.f;
            #pragma unroll 2
            for (int l = 0; l < TT; ++l) {
                const float de   = dl[l][e];
                const float dexc = de * xcs[l][e];
                const float4 B0 = *(const float4*)&Bs[l][n0];
                const float4 B1 = *(const float4*)&Bs[l][n0 + 4];
                float a;
                a = __expf(de * Aen[0]); hs[0] = fmaf(a, hs[0], B0.x * dexc);
                a = __expf(de * Aen[1]); hs[1] = fmaf(a, hs[1], B0.y * dexc);
                a = __expf(de * Aen[2]); hs[2] = fmaf(a, hs[2], B0.z * dexc);
                a = __expf(de * Aen[3]); hs[3] = fmaf(a, hs[3], B0.w * dexc);
                a = __expf(de * Aen[4]); hs[4] = fmaf(a, hs[4], B1.x * dexc);
                a = __expf(de * Aen[5]); hs[5] = fmaf(a, hs[5], B1.y * dexc);
                a = __expf(de * Aen[6]); hs[6] = fmaf(a, hs[6], B1.z * dexc);
                a = __expf(de * Aen[7]); hs[7] = fmaf(a, hs[7], B1.w * dexc);
            }
            const size_t idx = (((size_t)b * NC + c) * ED + e) * NST + n0;
            *(float4*)(hloc + idx)     = make_float4(hs[0], hs[1], hs[2], hs[3]);
            *(float4*)(hloc + idx + 4) = make_float4(hs[4], hs[5], hs[6], hs[7]);
            *(float4*)(aprod + idx) =
                make_float4(__expf(Aen[0] * dsum), __expf(Aen[1] * dsum),
                            __expf(Aen[2] * dsum), __expf(Aen[3] * dsum));
            *(float4*)(aprod + idx + 4) =
                make_float4(__expf(Aen[4] * dsum), __expf(Aen[5] * dsum),
                            __expf(Aen[6] * dsum), __expf(Aen[7] * dsum));
        }
    }
}

// ---------------- K3b: chunk combine (256 blocks x 64 threads, all 256 CUs).
// final==1: fused classifier head — each thread's post-loop h IS hend(b,e,n);
// reduce h·C[L-1] over n, gate, dot with fc_w, atomicAdd into out[b].
__global__ __launch_bounds__(64) void k_scan_combine(
    const float* __restrict__ aprod, float* __restrict__ hloc,
    const float* __restrict__ Cv, const float* __restrict__ xc,
    const float* __restrict__ zb, const float* __restrict__ Dp,
    const float* __restrict__ fcw, const float* __restrict__ fcb,
    float* __restrict__ out, int final)
{
    const int t = blockIdx.x * 64 + threadIdx.x;      // 0..16383
    const int b = t >> 12;                            // ED*NST = 4096
    const int en = t & 4095;
    size_t idx = (size_t)b * NC * (ED * NST) + en;
    float h = 0.f;
    #pragma unroll 4
    for (int c = 0; c < NC; ++c) {
        const float a = aprod[idx];
        const float u = hloc[idx];
        hloc[idx] = h;                 // initial state for chunk c
        h = fmaf(a, h, u);
        idx += ED * NST;
    }
    if (final) {
        const int e = en >> 5, n = en & 31;
        const size_t tok = (size_t)b * Lseq + (Lseq - 1);
        float p = h * Cv[tok * NST + n];
        #pragma unroll
        for (int off = 16; off; off >>= 1) p += __shfl_xor(p, off, 32);
        if (n == 0) {
            const float xce = xc[tok * ED + e];
            const float zi  = zb[tok * ED + e];
            float val = (p + Dp[e] * xce) * (zi * sigf(zi)) * fcw[e];
            if (en == 0) val += fcb[0];
            atomicAdd(&out[b], val);
        }
    }
}

// ---------------- K_C (layers 1..3): scan(y in LDS) + outproj + residual + rms + inproj
__global__ __launch_bounds__(256) void k_scan_gemm(
    const float* __restrict__ delta, const float* __restrict__ Bv,
    const float* __restrict__ Cv, const float* __restrict__ xc,
    const float* __restrict__ zbin, const float* __restrict__ A_log,
    const float* __restrict__ Dp, const float* __restrict__ hinit,
    const float* __restrict__ ow, const float* __restrict__ ob,
    const float* __restrict__ hin, const float* __restrict__ norm_w,
    const float* __restrict__ in_w, const float* __restrict__ in_b,
    float* __restrict__ hout, float* __restrict__ xin, float* __restrict__ zb)
{
    const int blk = blockIdx.x;             // BSZ * NC = 512
    const int b   = blk >> 7;
    const int c   = blk & 127;
    const int l0  = c * TT;
    const size_t t0 = (size_t)b * Lseq + l0;
    const int tid = threadIdx.x;
    const int e = tid & 127, half = tid >> 7;

    __shared__ __align__(16) float dlS[TT][ED];
    __shared__ __align__(16) float xcS[TT][ED];
    __shared__ __align__(16) float BsS[TT][NST];
    __shared__ __align__(16) float CsS[TT][NST];
    __shared__ __align__(16) float ys[TT][ED];
    __shared__ __align__(16) float pp[2][TT][ED];
    __shared__ __align__(16) float hn[TT][DM];

    // hoisted Aen (overlap with staging)
    float Aen16[16];
    {
        const float4* a4 = (const float4*)(A_log + e * NST + half * 16);
        #pragma unroll
        for (int i = 0; i < 4; ++i) {
            float4 v = a4[i];
            Aen16[i*4+0] = -__expf(v.x); Aen16[i*4+1] = -__expf(v.y);
            Aen16[i*4+2] = -__expf(v.z); Aen16[i*4+3] = -__expf(v.w);
        }
    }

    {
        const float4* dsrc = (const float4*)(delta + t0 * ED);
        const float4* xsrc = (const float4*)(xc + t0 * ED);
        float4* ddst = (float4*)&dlS[0][0];
        float4* xdst = (float4*)&xcS[0][0];
        #pragma unroll
        for (int i = 0; i < 2; ++i) {
            ddst[tid + i * 256] = dsrc[tid + i * 256];
            xdst[tid + i * 256] = xsrc[tid + i * 256];
        }
        if (tid < 128) {
            ((float4*)&BsS[0][0])[tid] = ((const float4*)(Bv + t0 * NST))[tid];
            ((float4*)&CsS[0][0])[tid] = ((const float4*)(Cv + t0 * NST))[tid];
        }
    }
    __syncthreads();

    #pragma unroll 1
    for (int g = 0; g < 2; ++g) {
        const int n0 = half * 16 + g * 8;
        float Aen[8];
        #pragma unroll
        for (int k = 0; k < 8; ++k) Aen[k] = Aen16[g * 8 + k];
        float hs[8];
        {
            const size_t idx = (((size_t)b * NC + c) * ED + e) * NST + n0;
            const float4 h0 = *(const float4*)(hinit + idx);
            const float4 h1 = *(const float4*)(hinit + idx + 4);
            hs[0] = h0.x; hs[1] = h0.y; hs[2] = h0.z; hs[3] = h0.w;
            hs[4] = h1.x; hs[5] = h1.y; hs[6] = h1.z; hs[7] = h1.w;
        }
        #pragma unroll 2
        for (int l = 0; l < TT; ++l) {
            const float de   = dlS[l][e];
            const float dexc = de * xcS[l][e];
            const float4 B0 = *(const float4*)&BsS[l][n0];
            const float4 B1 = *(const float4*)&BsS[l][n0 + 4];
            const float4 C0 = *(const float4*)&CsS[l][n0];
            const float4 C1 = *(const float4*)&CsS[l][n0 + 4];
            float a, p = 0.f;
            a = __expf(de * Aen[0]); hs[0] = fmaf(a, hs[0], B0.x * dexc); p = fmaf(hs[0], C0.x, p);
            a = __expf(de * Aen[1]); hs[1] = fmaf(a, hs[1], B0.y * dexc); p = fmaf(hs[1], C0.y, p);
            a = __expf(de * Aen[2]); hs[2] = fmaf(a, hs[2], B0.z * dexc); p = fmaf(hs[2], C0.z, p);
            a = __expf(de * Aen[3]); hs[3] = fmaf(a, hs[3], B0.w * dexc); p = fmaf(hs[3], C0.w, p);
            a = __expf(de * Aen[4]); hs[4] = fmaf(a, hs[4], B1.x * dexc); p = fmaf(hs[4], C1.x, p);
            a = __expf(de * Aen[5]); hs[5] = fmaf(a, hs[5], B1.y * dexc); p = fmaf(hs[5], C1.y, p);
            a = __expf(de * Aen[6]); hs[6] = fmaf(a, hs[6], B1.z * dexc); p = fmaf(hs[6], C1.z, p);
            a = __expf(de * Aen[7]); hs[7] = fmaf(a, hs[7], B1.w * dexc); p = fmaf(hs[7], C1.w, p);
            if (g == 0) pp[half][l][e] = p;
            else        pp[half][l][e] += p;
        }
    }
    __syncthreads();
    {
        const float dpe = Dp[e];
        #pragma unroll 2
        for (int j = 0; j < 8; ++j) {
            const int tl = half * 8 + j;
            const size_t tok = t0 + tl;
            const float p = pp[0][tl][e] + pp[1][tl][e];
            const float zi = zbin[tok * ED + e];
            ys[tl][e] = (p + dpe * xcS[tl][e]) * (zi * sigf(zi));
        }
    }
    __syncthreads();

    const int lane = tid & 63;
    const int wv = tid >> 6;
    const float nw = norm_w[lane];
    float hval[4];
    {
        float4 acc[4];
        #pragma unroll
        for (int j = 0; j < 4; ++j) acc[j] = make_float4(0.f, 0.f, 0.f, 0.f);
        #pragma unroll 1
        for (int p = 0; p < 4; ++p) {
            float4 w4[8];
            const float4* wr = (const float4*)(ow + lane * ED + p * 32);
            #pragma unroll
            for (int q = 0; q < 8; ++q) w4[q] = wr[q];
            #pragma unroll
            for (int j = 0; j < 4; ++j) {
                const float4* yv = (const float4*)&ys[wv * 4 + j][p * 32];
                #pragma unroll
                for (int q = 0; q < 8; ++q) {
                    float4 hv = yv[q];
                    acc[j].x = fmaf(hv.x, w4[q].x, acc[j].x);
                    acc[j].y = fmaf(hv.y, w4[q].y, acc[j].y);
                    acc[j].z = fmaf(hv.z, w4[q].z, acc[j].z);
                    acc[j].w = fmaf(hv.w, w4[q].w, acc[j].w);
                }
            }
        }
        const float obd = ob[lane];
        #pragma unroll
        for (int j = 0; j < 4; ++j) {
            const size_t tok = t0 + wv * 4 + j;
            hval[j] = hsum4(acc[j]) + obd + hin[tok * DM + lane];
            hout[tok * DM + lane] = hval[j];
        }
    }
    #pragma unroll
    for (int j = 0; j < 4; ++j) {
        float ss = hval[j] * hval[j];
        #pragma unroll
        for (int off = 32; off; off >>= 1) ss += __shfl_xor(ss, off, 64);
        const float sc = rsqrtf(ss * (1.0f / DM) + EPSV);
        hn[wv * 4 + j][lane] = hval[j] * sc * nw;
    }
    __syncthreads();
    inproj16(in_w, in_b, (const float (*)[DM])hn, xin, zb, t0, tid);
}

extern "C" void kernel_launch(void* const* d_in, const int* in_sizes, int n_in,
                              void* d_out, int out_size, void* d_ws, size_t ws_size,
                              hipStream_t stream)
{
    const float* x         = (const float*)d_in[0];
    const float* in_w      = (const float*)d_in[1];
    const float* in_b      = (const float*)d_in[2];
    const float* conv_w    = (const float*)d_in[3];
    const float* conv_b    = (const float*)d_in[4];
    const float* xproj_w   = (const float*)d_in[5];
    const float* dtproj_w  = (const float*)d_in[6];
    const float* dtproj_b  = (const float*)d_in[7];
    const float* A_log     = (const float*)d_in[8];
    const float* Dp        = (const float*)d_in[9];
    const float* outproj_w = (const float*)d_in[10];
    const float* outproj_b = (const float*)d_in[11];
    const float* norm_w    = (const float*)d_in[12];
    const float* fc_w      = (const float*)d_in[13];
    const float* fc_b      = (const float*)d_in[14];

    const size_t TOK = (size_t)BSZ * Lseq;
    float* ws = (float*)d_ws;
    float* h0    = ws; ws += TOK * DM;
    float* h1    = ws; ws += TOK * DM;
    float* xin   = ws; ws += TOK * ED;
    float* zbuf  = ws; ws += TOK * ED;
    float* xc    = ws; ws += TOK * ED;
    float* dlt   = ws; ws += TOK * ED;
    float* Bv    = ws; ws += TOK * NST;
    float* Cv    = ws; ws += TOK * NST;
    float* aprod = ws; ws += (size_t)BSZ * NC * ED * NST;   // 8 MB
    float* hloc  = ws; ws += (size_t)BSZ * NC * ED * NST;   // 8 MB, becomes hinit

    const float* hres = x;
    float* hbufs[2] = { h0, h1 };

    k_layer_gemm<<<(int)(TOK / TT), 256, 0, stream>>>(
        x, norm_w, in_w, in_b, xin, zbuf, (float*)d_out);

    for (int i = 0; i < NLAYERS; ++i) {
        const int last = (i == NLAYERS - 1);
        const float* Alog_i = A_log + (size_t)i * ED * NST;
        k_conv_scan<<<(int)(BSZ * NC), 256, 0, stream>>>(
            xin, conv_w + (size_t)i * ED * DCONVK, conv_b + (size_t)i * ED,
            xproj_w + (size_t)i * (DTRANK + 2 * NST) * ED,
            dtproj_w + (size_t)i * ED * DTRANK, dtproj_b + (size_t)i * ED,
            Alog_i, xc, dlt, Bv, Cv, aprod, hloc, last ? 0 : 1);
        k_scan_combine<<<(BSZ * ED * NST) / 64, 64, 0, stream>>>(
            aprod, hloc, Cv, xc, zbuf, Dp + (size_t)i * ED,
            fc_w, fc_b, (float*)d_out, last ? 1 : 0);
        if (!last) {
            float* hout = hbufs[i & 1];
            k_scan_gemm<<<(int)(BSZ * NC), 256, 0, stream>>>(
                dlt, Bv, Cv, xc, zbuf, Alog_i, Dp + (size_t)i * ED, hloc,
                outproj_w + (size_t)i * DM * ED, outproj_b + (size_t)i * DM,
                hres, norm_w + (size_t)(i + 1) * DM,
                in_w + (size_t)(i + 1) * 2 * ED * DM,
                in_b + (size_t)(i + 1) * 2 * ED,
                hout, xin, zbuf);
            hres = hout;
        }
    }
}